// Round 9
// baseline (231.597 us; speedup 1.0000x reference)
//
#include <hip/hip_runtime.h>
#include <hip/hip_bf16.h>

// B=2, L=4096, D=768, H=12, HS=64, SCALE=0.125. Inputs/outputs fp32; bf16 MFMA inside.
#define LQ 4096
#define DQ 768
#define NH 12
#define NB 2

typedef __attribute__((ext_vector_type(8))) short short8;
typedef __attribute__((ext_vector_type(2))) unsigned uint2v;
typedef __attribute__((ext_vector_type(4))) float f32x4;

__device__ __forceinline__ short f2bf(float f) {
    union { float f; unsigned u; } v; v.f = f;
    unsigned r = v.u + 0x7FFFu + ((v.u >> 16) & 1u);   // RNE
    return (short)(r >> 16);
}

__device__ __forceinline__ unsigned pk2(float a, float b) {
    float2 t; t.x = a; t.y = b;
    __hip_bfloat162 h = __float22bfloat162_rn(t);
    unsigned u; __builtin_memcpy(&u, &h, 4);
    return u;
}

__device__ __forceinline__ f32x4 mfma16(short8 a, short8 b, f32x4 c) {
    return __builtin_amdgcn_mfma_f32_16x16x32_bf16(a, b, c, 0, 0, 0);
}

// async 16B global->LDS DMA (dest = wave-uniform base + lane*16)
__device__ __forceinline__ void gld16(const short* g, short* l) {
    __builtin_amdgcn_global_load_lds(
        (const __attribute__((address_space(1))) unsigned int*)(g),
        (__attribute__((address_space(3))) unsigned int*)(l), 16, 0, 0);
}

// sqrt(0.125 * log2(e)): Qf pre-scaled so S^T = (Q')(Q')^T is directly in exp2 domain
#define SQRT_C 0.424660891f

// fp32 -> bf16 bulk convert, n multiple of 1024
__global__ __launch_bounds__(256) void cvtw(const float* __restrict__ a,
                                            short* __restrict__ o) {
    int i = blockIdx.x * 256 + threadIdx.x;
    float4 v = ((const float4*)a)[i];
    *(uint2v*)&o[i * 4] = (uint2v){pk2(v.x, v.y), pk2(v.z, v.w)};
}

// Fragment-major layouts (per bh, per 64-key tile = 4096 shorts, 8 chunks of 512):
//  Qf chunk(t4,s): lane L holds Q[key=16*t4+(L&15)][d=32*s+8*(L>>4)+j]  (SCALED by SQRT_C)
//  Vf chunk(t2,ks): lane L holds Q[key=32*ks+8*(L>>4)+j][d=16*t2+(L&15)] (unscaled)
// Chunk layout is LINEAR in key: 32-key sub-tile kb reads Qf at kb*2048 + (t4*2+s)*512.

// C[M,N] = A[M,K] @ Wb[N,K]^T, M=8192, N=768, K=768. A and Wb both bf16 (pre-cvt).
// ROUND-9 (T4): every prior gemm variant drained vmcnt(0) at each per-kt __syncthreads
// -- the m97 barrier-drain stall, with <=2 blocks/CU and nothing to hide it. All five
// variants landed within noise, consistent with the drain (not staging structure)
// being the limiter. Now: TRIPLE-buffered LDS (120KB, 1 block/CU), raw s_barrier,
// counted s_waitcnt vmcnt(5): compute(kt) waits only for loads issued TWO kts
// (~1900cy) earlier -> always complete; vmcnt never drained to 0 in-loop (T4/m218).
// Order per kt: waitcnt(stage kt done) -> barrier -> issue stage(kt+2) -> compute(kt).
// WAR safe: stage(kt+2) writes buf[(kt+2)%3], whose last readers (iter kt-1) are
// behind this iter's barrier; ds_reads complete before barrier-arrival (lgkm waits
// precede the MFMAs that consume them). Geometry = round-5/8: BM=128 BN=192 BK=64,
// 512 thr = 8 waves of 64x48 out, 256 blocks = 1/CU, XCD-affine mt, G21 XOR swizzle.
// MODE 0: C fp32 row-major. MODE 1: 3-head fragment scatter (verified r5-r8),
// now with an explicit leading __syncthreads (loop no longer ends with one).
template <int MODE>
__global__ __launch_bounds__(512, 2) void gemm_nt(const short* __restrict__ A,
                                                  const short* __restrict__ Wb,
                                                  void* __restrict__ Cp,
                                                  short* __restrict__ Vf) {
    // carve: As[3][8192] = smem[0..24576), Bs[3][12288] = smem[24576..61440)
    __shared__ __attribute__((aligned(16))) short smem[61440];   // 120 KB
    const int t = threadIdx.x;
    const int lane = t & 63, w = t >> 6;                 // 8 waves
    const int lr = lane & 15, qd = lane >> 4;
    const int wm = (w >> 2) * 64, wn = (w & 3) * 48;     // wave tile 64m x 48n
    const int lin = blockIdx.x;
    const int xcd = lin & 7, jj = lin >> 3;              // 256 blocks, 8 XCDs
    const int nt = jj & 3, mt = (jj >> 2) * 8 + xcd;     // 4 n-tiles x 64 m-tiles
    const int m0 = mt * 128, n0 = nt * 192;

    // kt-invariant per-lane source offsets (XOR-swizzled chunk within each 8-chunk row)
    int aoffs[2], boffs[3];
#pragma unroll
    for (int u = 0; u < 2; ++u) {
        int c = (u * 8 + w) * 64 + lane;                 // A 16B-unit id 0..1023
        int row = c >> 3, k = (c & 7) ^ (row & 7);
        aoffs[u] = (m0 + row) * DQ + k * 8;
    }
#pragma unroll
    for (int u = 0; u < 3; ++u) {
        int c = (u * 8 + w) * 64 + lane;                 // B 16B-unit id 0..1535
        int row = c >> 3, k = (c & 7) ^ (row & 7);
        boffs[u] = (n0 + row) * DQ + k * 8;
    }

    f32x4 acc[4][3];
#pragma unroll
    for (int i = 0; i < 4; ++i)
#pragma unroll
        for (int j = 0; j < 3; ++j) acc[i][j] = (f32x4){0.f, 0.f, 0.f, 0.f};

    // stage K-tile s into LDS buffer s%3 (5 gld16 per wave)
    auto STAGE = [&](int s) {
        const int b3 = s - (s / 3) * 3, k0 = s * 64;
#pragma unroll
        for (int u = 0; u < 2; ++u)
            gld16(&A[aoffs[u] + k0], &smem[b3 * 8192 + (u * 8 + w) * 512]);
#pragma unroll
        for (int u = 0; u < 3; ++u)
            gld16(&Wb[boffs[u] + k0], &smem[24576 + b3 * 12288 + (u * 8 + w) * 512]);
    };

    STAGE(0);
    STAGE(1);                                            // 10 loads in flight

#pragma unroll 1
    for (int kt = 0; kt < 12; ++kt) {
        // wait for stage(kt) only: leave stage(kt+1)'s 5 loads in flight (T4)
        if (kt < 11) asm volatile("s_waitcnt vmcnt(5)" ::: "memory");
        else         asm volatile("s_waitcnt vmcnt(0)" ::: "memory");
        asm volatile("s_barrier" ::: "memory");          // all waves' stage(kt) visible
        if (kt < 10) STAGE(kt + 2);                      // deep prefetch, never drained

        const int b3 = kt - (kt / 3) * 3;
        const short* Asb = &smem[b3 * 8192];
        const short* Bsb = &smem[24576 + b3 * 12288];
#pragma unroll
        for (int s = 0; s < 2; ++s) {
            const int cq = ((4 * s + qd) ^ (lr & 7)) * 8;    // un-swizzle chunk position
            short8 af[4], bf[3];
#pragma unroll
            for (int i = 0; i < 4; ++i)
                af[i] = *(const short8*)&Asb[(wm + 16 * i + lr) * 64 + cq];
#pragma unroll
            for (int j = 0; j < 3; ++j)
                bf[j] = *(const short8*)&Bsb[(wn + 16 * j + lr) * 64 + cq];
#pragma unroll
            for (int i = 0; i < 4; ++i)
#pragma unroll
                for (int j = 0; j < 3; ++j)
                    acc[i][j] = mfma16(af[i], bf[j], acc[i][j]);
        }
    }

    if (MODE == 0) {
#pragma unroll
        for (int i = 0; i < 4; ++i)
#pragma unroll
            for (int j = 0; j < 3; ++j) {
                const int row0 = m0 + wm + 16 * i + qd * 4;
                const int col = n0 + wn + 16 * j + lr;
#pragma unroll
                for (int r = 0; r < 4; ++r)
                    ((float*)Cp)[(size_t)(row0 + r) * DQ + col] = acc[i][j][r];
            }
    } else {
        // block tile = keys kl0..kl0+127 of 3 heads {nt*3, +1, +2} of batch m0>>12.
        short* Qf = (short*)Cp;
        short* F = smem;                                 // 24576-short scratch [3][8192]
        const int bh0 = (m0 >> 12) * NH + nt * 3;
        const int kl0 = m0 & 4095;
        __syncthreads();                                 // laggards may still read As
        // ---- Vf staging (unscaled): packed b64 scatter ----
#pragma unroll
        for (int i = 0; i < 4; ++i)
#pragma unroll
            for (int j = 0; j < 3; ++j) {
                const int kl = wm + 16 * i + qd * 4;     // key 0..127 (4 consecutive)
                const int hsg = wn + 16 * j + lr;        // global d 0..191
                const int hh = hsg >> 6, hs = hsg & 63;
                const int fi = hh * 8192 + ((kl >> 6) & 1) * 4096
                             + ((((hs >> 4) << 1) + ((kl >> 5) & 1)) << 9)
                             + (((hs & 15) + (((kl >> 3) & 3) << 4)) << 3) + (kl & 7);
                *(uint2v*)&F[fi] = (uint2v){pk2(acc[i][j][0], acc[i][j][1]),
                                            pk2(acc[i][j][2], acc[i][j][3])};
            }
        __syncthreads();
#pragma unroll
        for (int p = 0; p < 6; ++p) {
            int u = t + 512 * p;                         // atom id 0..3071
            int hh = u >> 10, rem = u & 1023;
            size_t g = (size_t)(bh0 + hh) * (LQ * 64) + (size_t)((kl0 >> 6) << 12);
            *(short8*)&Vf[g + (size_t)rem * 8] = *(short8*)&F[u * 8];
        }
        __syncthreads();
        // ---- Qf staging (scaled by SQRT_C): b16 scatter ----
#pragma unroll
        for (int i = 0; i < 4; ++i)
#pragma unroll
            for (int j = 0; j < 3; ++j) {
                const int hsg = wn + 16 * j + lr;
                const int hh = hsg >> 6, hs = hsg & 63;
#pragma unroll
                for (int r = 0; r < 4; ++r) {
                    const int key = wm + 16 * i + qd * 4 + r;
                    const int fi = hh * 8192 + ((key >> 6) & 1) * 4096
                                 + (((((key >> 4) & 3) << 1) + (hs >> 5)) << 9)
                                 + (((qd * 4 + r) + (((hs >> 3) & 3) << 4)) << 3) + (hs & 7);
                    F[fi] = f2bf(acc[i][j][r] * SQRT_C);
                }
            }
        __syncthreads();
#pragma unroll
        for (int p = 0; p < 6; ++p) {
            int u = t + 512 * p;
            int hh = u >> 10, rem = u & 1023;
            size_t g = (size_t)(bh0 + hh) * (LQ * 64) + (size_t)((kl0 >> 6) << 12);
            *(short8*)&Qf[g + (size_t)rem * 8] = *(short8*)&F[u * 8];
        }
    }
}

// Split-K-in-block flash attention, K=V=Q, shift-0 softmax, fragment-major loads.
// FROZEN round-8 best (127.1us): 4-wave (256t) blocks = {2 q-groups of 64q} x
// {2 key-halves of 2048k}; 768 blocks = 3/CU = 12 waves/CU; (256,3) = ~170 unified
// regs/wave (live set ~150: ANY cap below ~170 spills catastrophically -- r1/r7).
// T5 s_setprio around MFMA clusters: proven +2us (r8 vs r4, same structure).
// Phase-separated so kf and vb register lifetimes never overlap; no in-loop barriers
// (r3: explicit prefetch only added pressure -- compiler already hoists maximally).
// Shift-0 softmax => partials over disjoint key ranges combine by pure addition:
// epilogue LDS exchange (fp32, stride 21*16B, conflict-free), half=0 waves add+normalize.
__global__ __launch_bounds__(256, 3) void attn(const short* __restrict__ Qf,
                                               const short* __restrict__ Vf,
                                               short* __restrict__ O) {
    const int linear = blockIdx.x;
    const int xcd = linear & 7, slot = linear >> 3;        // 768 blocks, 8 XCDs
    const int bh = 3 * xcd + (slot >> 5);                  // 3 bh per XCD (L2-resident)
    const int qtile = slot & 31;                           // 32 q-tiles of 128
    const int t = threadIdx.x;
    const int lane = t & 63, w = t >> 6;                   // w in {0..3}
    const int qw = w & 1, half = w >> 1;                   // q-group, key-half
    const int lr = lane & 15, qd = lane >> 4;

    // LDS: aqs [2 qw][4096] shorts (16384B) + Ps [4 w][4 chains][16*40] shorts (20480B)
    // = 36864B, all aliased with the 43008B fp32 exchange buffer used after the loop.
    __shared__ alignas(16) char smem[43008];
    short* aqs = (short*)smem;                             // Q fragments, per q-group
    short* Ps = (short*)(smem + 16384) + w * 2560;         // per-wave P scratch (shorts)

    const short* Qbh = Qf + (size_t)bh * (LQ * 64);
    const short* Vbh = Vf + (size_t)bh * (LQ * 64);
    const int q0 = qtile * 128 + qw * 64;
    const int kb0 = half * 64;                             // 32-key tiles: 0..63 / 64..127

    const short one_bf = (short)0x3F80;                    // bf16 1.0
    short8 ones;
#pragma unroll
    for (int j = 0; j < 8; ++j) ones[j] = one_bf;

    // ---- stage this block's 128q Q-fragments into LDS (both q-groups, linear copy) ----
#pragma unroll
    for (int p = 0; p < 4; ++p) {
        int off = (t + 256 * p) * 8;                       // 0..8191 shorts
        *(short8*)&aqs[off] = *(const short8*)&Qbh[(size_t)qtile * 8192 + off];
    }
    __syncthreads();

    f32x4 oacc[4][4], lacc[4];
#pragma unroll
    for (int i = 0; i < 4; ++i) {
        lacc[i] = (f32x4){0.f, 0.f, 0.f, 0.f};
#pragma unroll
        for (int t2 = 0; t2 < 4; ++t2) oacc[i][t2] = (f32x4){0.f, 0.f, 0.f, 0.f};
    }

    const int aqbase = qw * 4096 + lane * 8;               // LDS index of this lane's aq

    for (int kb = kb0; kb < kb0 + 64; ++kb) {
        // ---- phase 1: K frags (32 keys) live; all 4 chains QK -> exp2 -> Ps ----
        short8 kf[2][2];
#pragma unroll
        for (int t4 = 0; t4 < 2; ++t4)
#pragma unroll
            for (int s = 0; s < 2; ++s)
                kf[t4][s] = *(const short8*)&Qbh[kb * 2048 + (t4 * 2 + s) * 512 + lane * 8];

#pragma unroll
        for (int i = 0; i < 4; ++i) {
            short8 aq0 = *(const short8*)&aqs[aqbase + i * 1024];
            short8 aq1 = *(const short8*)&aqs[aqbase + i * 1024 + 512];
            f32x4 s0 = (f32x4){0.f, 0.f, 0.f, 0.f};
            f32x4 s1 = (f32x4){0.f, 0.f, 0.f, 0.f};
            __builtin_amdgcn_s_setprio(1);                 // T5: favor MFMA cluster
            s0 = mfma16(kf[0][0], aq0, s0);
            s0 = mfma16(kf[0][1], aq1, s0);
            s1 = mfma16(kf[1][0], aq0, s1);
            s1 = mfma16(kf[1][1], aq1, s1);
            __builtin_amdgcn_s_setprio(0);
            // lane holds S^T[key=16*t4+qd*4+r][q=lr], already in exp2 domain
            *(uint2v*)&Ps[i * 640 + lr * 40 + 4 * qd] =
                (uint2v){pk2(__builtin_amdgcn_exp2f(s0[0]), __builtin_amdgcn_exp2f(s0[1])),
                         pk2(__builtin_amdgcn_exp2f(s0[2]), __builtin_amdgcn_exp2f(s0[3]))};
            *(uint2v*)&Ps[i * 640 + lr * 40 + 16 + 4 * qd] =
                (uint2v){pk2(__builtin_amdgcn_exp2f(s1[0]), __builtin_amdgcn_exp2f(s1[1])),
                         pk2(__builtin_amdgcn_exp2f(s1[2]), __builtin_amdgcn_exp2f(s1[3]))};
        }

        // ---- phase 2: kf dead; V^T frags (32 keys) live; all 4 chains PV + l ----
        short8 vb[4];
#pragma unroll
        for (int t2 = 0; t2 < 4; ++t2)
            vb[t2] = *(const short8*)&Vbh[(kb >> 1) * 4096 + (kb & 1) * 512 + t2 * 1024 + lane * 8];

        __builtin_amdgcn_s_setprio(1);                     // T5: PV is MFMA-dominated
#pragma unroll
        for (int i = 0; i < 4; ++i) {
            short8 pa = *(short8*)&Ps[i * 640 + lr * 40 + qd * 8];
#pragma unroll
            for (int t2 = 0; t2 < 4; ++t2)
                oacc[i][t2] = mfma16(pa, vb[t2], oacc[i][t2]);
            lacc[i] = mfma16(pa, ones, lacc[i]);           // row-sum on the MFMA pipe
        }
        __builtin_amdgcn_s_setprio(0);
    }

    // ---- split-K combine: half=1 waves publish fp32 partials, half=0 waves reduce ----
    __syncthreads();                                       // Ps/aqs dead from here; alias ok
    f32x4* ex = (f32x4*)smem + (qw * 64 + lane) * 21;      // stride 21: bank-conflict-free
    if (half) {
#pragma unroll
        for (int i = 0; i < 4; ++i) {
#pragma unroll
            for (int t2 = 0; t2 < 4; ++t2) ex[i * 4 + t2] = oacc[i][t2];
            ex[16 + i] = lacc[i];
        }
    }
    __syncthreads();
    if (half) return;

#pragma unroll
    for (int i = 0; i < 4; ++i) {
#pragma unroll
        for (int t2 = 0; t2 < 4; ++t2) oacc[i][t2] += ex[i * 4 + t2];
        lacc[i] += ex[16 + i];
    }

    // l for query qd*4+r is lacc[i][r] in every lane; normalize; store O[b][l][h*64+e]
    const int b = bh / NH, h = bh % NH;
#pragma unroll
    for (int i = 0; i < 4; ++i) {
        float inv[4];
#pragma unroll
        for (int r = 0; r < 4; ++r) inv[r] = 1.0f / lacc[i][r];
#pragma unroll
        for (int t2 = 0; t2 < 4; ++t2)
#pragma unroll
            for (int r = 0; r < 4; ++r) {
                int lq = q0 + 16 * i + qd * 4 + r;
                int e = h * 64 + 16 * t2 + lr;
                O[((size_t)(b * LQ + lq)) * DQ + e] = f2bf(oacc[i][t2][r] * inv[r]);
            }
    }
}

extern "C" void kernel_launch(void* const* d_in, const int* in_sizes, int n_in,
                              void* d_out, int out_size, void* d_ws, size_t ws_size,
                              hipStream_t stream) {
    (void)in_sizes; (void)n_in; (void)out_size; (void)ws_size;
    const float* x  = (const float*)d_in[0];   // fp32 [2,4096,768]
    const float* Wq = (const float*)d_in[1];   // fp32 [768,768]
    const float* Wo = (const float*)d_in[2];   // fp32 [768,768]
    float* out = (float*)d_out;                // fp32 [2,4096,768]

    const size_t NQ = (size_t)NB * NH * LQ * 64;         // 6,291,456 elements
    const size_t NW = (size_t)DQ * DQ;                   // 589,824 elements
    short* Qf  = (short*)d_ws;                           // fragment-major scaled Q
    short* Vfb = Qf + NQ;                                // fragment-major unscaled Q (V)
    short* Ows = Vfb + NQ;                               // xb, then attention out
    short* Wqb = Ows + (size_t)NB * LQ * DQ;             // bf16 Wq
    short* Wob = Wqb + NW;                               // bf16 Wo

    // 1) x -> bf16 (into Ows slot); Wq/Wo -> bf16 once
    cvtw<<<(NB * LQ * DQ) / 1024, 256, 0, stream>>>(x, Ows);
    cvtw<<<NW / 1024, 256, 0, stream>>>(Wq, Wqb);
    cvtw<<<NW / 1024, 256, 0, stream>>>(Wo, Wob);
    // 2) Q-projection -> fragment-major Qf (scaled) + Vf (T4 counted-vmcnt gemm)
    gemm_nt<1><<<256, 512, 0, stream>>>(Ows, Wqb, Qf, Vfb);
    // 3) split-K flash attention (K=V=Q), 12 waves/CU, T5 setprio -> Ows
    attn<<<768, 256, 0, stream>>>(Qf, Vfb, Ows);
    // 4) out = O @ bf16(Wo)^T, fp32 store (T4 counted-vmcnt gemm)
    gemm_nt<0><<<256, 512, 0, stream>>>(Ows, Wob, out, nullptr);
}